// Round 4
// baseline (229.211 us; speedup 1.0000x reference)
//
#include <hip/hip_runtime.h>

// Blur = UpFirDn2D(up=2, dn=2, k=4x4 outer([1,3,3,1])/16) collapses to a
// 2x2 stencil (only odd taps hit non-zero interleaved samples):
//   out[i][j] = F[1][1]*x[i][j] + F[1][3]*x[i][j+1]
//             + F[3][1]*x[i+1][j] + F[3][3]*x[i+1][j+1],  OOB x = 0.
// Memory-bound: ~268 MB min traffic -> ~43 us floor at 6.3-6.6 TB/s.
//
// R2/R3: 2 output rows per thread (rows 2p, 2p+1; loads rows 2p..2p+2).
// Read amplification 2x -> 1.5x, and the redundant even-row read is
// intra-block (thread +32) -> L1 hit. Stores nontemporal (no reuse) via
// native ext_vector_type (HIP float4 class rejected by the builtin).
// Neighbor (j+4) taps via shfl_down(1) (lane+1 holds next float4 of the
// same row for q<31; q==31 masked to 0 = right-edge zero pad).

constexpr int NB = 8, NC = 256, H = 128, W = 128;

typedef float v4f __attribute__((ext_vector_type(4)));

__global__ __launch_bounds__(256) void blur_kernel(
    const float* __restrict__ x,
    const float* __restrict__ filt,
    float* __restrict__ out)
{
    int t = blockIdx.x * blockDim.x + threadIdx.x;
    // threads = (NB*NC) * (H/2 row-pairs) * (W/4) = 2048*64*32 = 4194304
    int q   = t & 31;          // float4 index within row (j = 4*q)
    int p   = (t >> 5) & 63;   // row pair: rows 2p, 2p+1
    int img = t >> 11;         // b*NC + c  (wave-uniform)
    int c   = img & (NC - 1);

    // channel is wave-uniform -> SGPR address -> s_load for weights
    int cu = __builtin_amdgcn_readfirstlane(c);
    const float* fb = filt + cu * 16;
    float w11 = fb[5], w13 = fb[7], w31 = fb[13], w33 = fb[15];

    const float* row0 = x + ((size_t)img * H + 2 * p) * W + (q << 2);
    v4f a = *(const v4f*)row0;            // row 2p
    v4f b = *(const v4f*)(row0 + W);      // row 2p+1
    v4f cc = (v4f)(0.0f);
    if (p < 63) cc = *(const v4f*)(row0 + 2 * W);  // row 2p+2

    // j+4 neighbor elements from the next lane (same row for q<31)
    float aR = __shfl_down(a.x, 1);
    float bR = __shfl_down(b.x, 1);
    float cR = __shfl_down(cc.x, 1);
    if (q == 31) { aR = 0.0f; bR = 0.0f; cR = 0.0f; }

    v4f o0, o1;
    o0.x = w11 * a.x + w13 * a.y + w31 * b.x + w33 * b.y;
    o0.y = w11 * a.y + w13 * a.z + w31 * b.y + w33 * b.z;
    o0.z = w11 * a.z + w13 * a.w + w31 * b.z + w33 * b.w;
    o0.w = w11 * a.w + w13 * aR  + w31 * b.w + w33 * bR;

    o1.x = w11 * b.x + w13 * b.y + w31 * cc.x + w33 * cc.y;
    o1.y = w11 * b.y + w13 * b.z + w31 * cc.y + w33 * cc.z;
    o1.z = w11 * b.z + w13 * b.w + w31 * cc.z + w33 * cc.w;
    o1.w = w11 * b.w + w13 * bR  + w31 * cc.w + w33 * cR;

    float* orow = out + ((size_t)img * H + 2 * p) * W + (q << 2);
    __builtin_nontemporal_store(o0, (v4f*)orow);
    __builtin_nontemporal_store(o1, (v4f*)(orow + W));
}

extern "C" void kernel_launch(void* const* d_in, const int* in_sizes, int n_in,
                              void* d_out, int out_size, void* d_ws, size_t ws_size,
                              hipStream_t stream)
{
    const float* x    = (const float*)d_in[0];
    const float* filt = (const float*)d_in[1];
    float* out        = (float*)d_out;

    const int total_threads = NB * NC * (H / 2) * (W / 4);  // 4194304
    const int block = 256;
    const int grid  = total_threads / block;                // 16384

    blur_kernel<<<grid, block, 0, stream>>>(x, filt, out);
}